// Round 1
// baseline (965.448 us; speedup 1.0000x reference)
//
#include <hip/hip_runtime.h>

#define BB 64
#define HH 32
#define KVH 8
#define HD 128
#define BS 16
#define MAXC 2048
#define MB 128
#define G 4
#define SPLIT 4
#define SPLIT_LEN 512
#define SPLIT_BLKS 32
#define PART_STRIDE 520   // 512 O floats + 4 m + 4 l
#define SCALE 0.08838834764831845f

// Partial flash-decode attention over one context split.
// grid = B*KVH*SPLIT (2048), block = 256 (4 waves)
__global__ __launch_bounds__(256) void attn_partial(
    const float* __restrict__ q,
    const float* __restrict__ knew,
    const float* __restrict__ vnew,
    const float* __restrict__ kc,
    const float* __restrict__ vc,
    const int* __restrict__ block_tables,
    const int* __restrict__ context_lens,
    float* __restrict__ ws)
{
    const int idx   = blockIdx.x;
    const int split = idx & (SPLIT - 1);
    const int kvh   = (idx >> 2) & (KVH - 1);
    const int b     = idx >> 5;
    const int tid   = threadIdx.x;
    const int w     = tid >> 6;      // wave 0..3
    const int lane  = tid & 63;
    const int half  = lane >> 5;
    const int l32   = lane & 31;

    const int ctx   = context_lens[b];
    const int start = split * SPLIT_LEN;
    const int n     = min(ctx - start, SPLIT_LEN);

    float* wbase = ws + (size_t)idx * PART_STRIDE;

    if (n <= 0) {
        // empty split: neutral partial (m=-inf, l=0, O=0)
        for (int i = tid; i < G * HD; i += 256) wbase[i] = 0.f;
        if (tid < G) { wbase[G * HD + tid] = -1e30f; wbase[G * HD + G + tid] = 0.f; }
        return;
    }

    __shared__ float sQ[G][HD];
    __shared__ float sS[G][SPLIT_LEN];
    __shared__ float sO[4][G][HD];
    __shared__ float sM[G], sL[G];
    __shared__ int   sBT[SPLIT_BLKS];

    for (int i = tid; i < G * HD; i += 256) {
        int h = i >> 7, d = i & (HD - 1);
        sQ[h][d] = q[((size_t)b * HH + kvh * G + h) * HD + d];
    }
    if (tid < SPLIT_BLKS)
        sBT[tid] = block_tables[b * MB + split * SPLIT_BLKS + tid];
    __syncthreads();

    // q fragments in registers: 4 heads x float4 (this lane's 4 dims)
    float4 rq[G];
    #pragma unroll
    for (int h = 0; h < G; h++) rq[h] = *(const float4*)&sQ[h][l32 * 4];

    const float4* fresh_k = (const float4*)(knew + ((size_t)b * KVH + kvh) * HD);

    // ---- Phase 1: scores (each 32-lane half loads one token's K row) ----
    for (int jb = 0; jb < n; jb += 16) {
        #pragma unroll
        for (int c = 0; c < 2; c++) {
            int j = jb + w * 4 + c * 2 + half;
            if (j < n) {
                int t    = start + j;
                int slot = sBT[j >> 4] * BS + (j & (BS - 1));
                const float4* kp = (t == ctx - 1) ? fresh_k
                    : (const float4*)(kc + ((size_t)slot * KVH + kvh) * HD);
                float4 kv = kp[l32];
                float p[G];
                #pragma unroll
                for (int h = 0; h < G; h++)
                    p[h] = rq[h].x * kv.x + rq[h].y * kv.y
                         + rq[h].z * kv.z + rq[h].w * kv.w;
                #pragma unroll
                for (int h = 0; h < G; h++) {
                    #pragma unroll
                    for (int m = 16; m >= 1; m >>= 1)
                        p[h] += __shfl_xor(p[h], m);   // stays within 32-lane half
                }
                if (l32 == 0) {
                    #pragma unroll
                    for (int h = 0; h < G; h++) sS[h][j] = p[h] * SCALE;
                }
            }
        }
    }
    __syncthreads();

    // ---- Phase 1.5: softmax per head (wave w owns head w) ----
    {
        float mx = -1e30f;
        for (int j = lane; j < n; j += 64) mx = fmaxf(mx, sS[w][j]);
        #pragma unroll
        for (int m = 32; m >= 1; m >>= 1) mx = fmaxf(mx, __shfl_xor(mx, m));
        float sm = 0.f;
        for (int j = lane; j < n; j += 64) {
            float p = __expf(sS[w][j] - mx);
            sS[w][j] = p;
            sm += p;
        }
        #pragma unroll
        for (int m = 32; m >= 1; m >>= 1) sm += __shfl_xor(sm, m);
        if (lane == 0) { sM[w] = mx; sL[w] = sm; }
    }
    __syncthreads();

    // ---- Phase 2: PV (full wave loads one token's V row as float2) ----
    float2 acc[G];
    #pragma unroll
    for (int h = 0; h < G; h++) acc[h] = make_float2(0.f, 0.f);

    const float2* fresh_v = (const float2*)(vnew + ((size_t)b * KVH + kvh) * HD);
    for (int j = w; j < n; j += 4) {
        int t    = start + j;
        int slot = sBT[j >> 4] * BS + (j & (BS - 1));
        const float2* vp = (t == ctx - 1) ? fresh_v
            : (const float2*)(vc + ((size_t)slot * KVH + kvh) * HD);
        float2 vv = vp[lane];
        #pragma unroll
        for (int h = 0; h < G; h++) {
            float p = sS[h][j];       // LDS broadcast
            acc[h].x += p * vv.x;
            acc[h].y += p * vv.y;
        }
    }
    #pragma unroll
    for (int h = 0; h < G; h++) {
        sO[w][h][2 * lane]     = acc[h].x;
        sO[w][h][2 * lane + 1] = acc[h].y;
    }
    __syncthreads();

    // cross-wave reduce; wave w writes head w's unnormalized O + (m,l)
    for (int d = lane; d < HD; d += 64) {
        float o = sO[0][w][d] + sO[1][w][d] + sO[2][w][d] + sO[3][w][d];
        wbase[w * HD + d] = o;
    }
    if (tid < G)                      wbase[G * HD + tid]     = sM[tid];
    else if (tid >= 64 && tid < 64+G) wbase[G * HD + G + tid - 64] = sL[tid - 64];
}

// Merge the SPLIT partials. grid = B*KVH (512), block = 512 (h = tid>>7, d = tid&127)
__global__ __launch_bounds__(512) void attn_combine(
    const float* __restrict__ ws, float* __restrict__ out)
{
    const int bk = blockIdx.x;           // b*KVH + kvh
    const int h  = threadIdx.x >> 7;
    const int d  = threadIdx.x & (HD - 1);
    const float* base = ws + (size_t)bk * SPLIT * PART_STRIDE;

    float M = -1e30f;
    #pragma unroll
    for (int s = 0; s < SPLIT; s++)
        M = fmaxf(M, base[s * PART_STRIDE + G * HD + h]);
    float L = 0.f, O = 0.f;
    #pragma unroll
    for (int s = 0; s < SPLIT; s++) {
        float e = __expf(base[s * PART_STRIDE + G * HD + h] - M);
        L += base[s * PART_STRIDE + G * HD + G + h] * e;
        O += base[s * PART_STRIDE + h * HD + d] * e;
    }
    const int b = bk >> 3, kvh = bk & (KVH - 1);
    out[((size_t)b * HH + kvh * G + h) * HD + d] = O / L;
}

extern "C" void kernel_launch(void* const* d_in, const int* in_sizes, int n_in,
                              void* d_out, int out_size, void* d_ws, size_t ws_size,
                              hipStream_t stream) {
    const float* q    = (const float*)d_in[0];
    const float* knew = (const float*)d_in[1];
    const float* vnew = (const float*)d_in[2];
    const float* kc   = (const float*)d_in[3];
    const float* vc   = (const float*)d_in[4];
    // d_in[5] = slot_mapping (unused: slot == block_tables[b][(ctx-1)/16]*16 + (ctx-1)%16)
    const int* bt   = (const int*)d_in[6];
    const int* clen = (const int*)d_in[7];
    float* out = (float*)d_out;
    float* ws  = (float*)d_ws;

    attn_partial<<<BB * KVH * SPLIT, 256, 0, stream>>>(q, knew, vnew, kc, vc, bt, clen, ws);
    attn_combine<<<BB * KVH, 512, 0, stream>>>(ws, out);
}